// Round 2
// baseline (398.557 us; speedup 1.0000x reference)
//
#include <hip/hip_runtime.h>
#include <math.h>

// Word_Graph_Attention R4: wave-per-tile (R3 structure) + R2-bit-exact softmax.
//
// R3 post-mortem: A/B fragments, bias, MFMA order were bit-identical to the
// verified R2, yet absmax jumped 3.9e-3 -> 3.76e-2. The reference has an
// exact-equality landmine: att = where(att == 1/50, 0, att), and softmax
// outputs cluster around 0.02 (random cosine scores are small). R3 computed
// att = e * (1/sm) (reciprocal-mul) instead of R2's/np's e / sm (division),
// rerolling the exact-hit lottery -> one accidental 0.02f mismatch = error
// 0.02*|K| ~= 0.0376 (observed). R4 restores R2's score/softmax arithmetic
// verbatim (np += kv*kv contraction, one-row-per-lane softmax, division),
// routed through small per-wave LDS arrays so waves stay barrier-free.
// Given bit-identical K, att is bit-identical to the passing R2.
//
// Structure (unchanged from R3): each wave owns one (b,s) tile end-to-end,
// ZERO per-tile barriers. A (v) loads global->reg in MFMA fragment order
// (no reuse). K tile stays in acc registers (50x112). Only Vw B-fragments
// (28KB, reused 16x/block) + Qn + 3KB per-wave softmax arrays in LDS.
//
// Verified layouts (from passing R2):
//   A-frag: lane l holds A[16*mt + (l&15)][c*32 + (l>>4)*8 + j], j=0..7
//   B-frag: lane l holds Vw[16*nt + (l&15)][c*32 + (l>>4)*8 + j]
//   C/D   : acc[mt][nt][r] = K[16*mt + 4*qd + r][16*nt + m]
// No d_ws use (R1 post-mortem: unchecked ws overflow corrupted inputs).

#define S_DIM 256
#define N_NBR 50
#define D_F   100
#define QD    768
#define NT    7      // 7 x 16 = 112 >= 100 output cols
#define KC    4      // 4 x 32 = 128 >= 100 contraction

typedef __attribute__((ext_vector_type(4))) float f32x4;
typedef __attribute__((ext_vector_type(8))) short s16x8;

__device__ __forceinline__ short f2bf(float f) {
  union { float f; unsigned u; } x; x.f = f;
  unsigned r = x.u + 0x7fffu + ((x.u >> 16) & 1u);   // RNE
  return (short)(r >> 16);
}

__global__ __launch_bounds__(256, 2) void wga_kernel(
    const float* __restrict__ v, const float* __restrict__ q,
    const float* __restrict__ Qw, const float* __restrict__ Qb,
    const float* __restrict__ Vw, const float* __restrict__ Vb,
    float* __restrict__ out) {
  __shared__ __align__(16) short BlS[28 * 64 * 8];   // 28 KB B fragments (bf16)
  __shared__ float qs[QD];
  __shared__ float Qpart[256];
  __shared__ float QnS[112];
  __shared__ float rnS;
  __shared__ float nrm2W[4][64], srwW[4][64], attW[4][64];  // per-wave, no races

  const int t  = threadIdx.x;
  const int w  = t >> 6, l = t & 63;
  const int qd = l >> 4, m = l & 15;
  const int blk = blockIdx.x;
  const int b   = blk >> 4;
  const int s0  = (blk & 15) << 4;

  // ---- stage q[b] ----
  for (int i = t; i < QD; i += 256) qs[i] = q[b * QD + i];

  // ---- stage B fragments: BlS[(c*7+nt)*64+ll] = Vw[16nt+(ll&15)][c*32+(ll>>4)*8+j] ----
  for (int idx = t; idx < 28 * 64; idx += 256) {
    const int g  = idx >> 6, ll = idx & 63;
    const int c  = g / 7, nt = g - 7 * c;
    const int col = nt * 16 + (ll & 15);
    const int k0  = c * 32 + (ll >> 4) * 8;
    s16x8 pk;
    if (c < 3 && col < D_F) {                        // fast path: k0+7 <= 95 < 100
      const f32x4 u0 = *(const f32x4*)(Vw + col * D_F + k0);
      const f32x4 u1 = *(const f32x4*)(Vw + col * D_F + k0 + 4);
#pragma unroll
      for (int j = 0; j < 4; ++j) { pk[j] = f2bf(u0[j]); pk[4 + j] = f2bf(u1[j]); }
    } else {
#pragma unroll
      for (int j = 0; j < 8; ++j) {
        const int k = k0 + j;
        pk[j] = f2bf((col < D_F && k < D_F) ? Vw[col * D_F + k] : 0.f);
      }
    }
    *(s16x8*)&BlS[idx * 8] = pk;
  }
  __syncthreads();

  // ---- Qn = normalize(q[b] @ Qw^T + Qb)  (verified R2 code, setup-only) ----
  if (t < 200) {
    const int e = t >> 1, h = t & 1;
    const float4* wr = (const float4*)(Qw + e * QD + h * 384);
    const float4* qv = (const float4*)(qs + h * 384);
    float a0 = 0.f, a1 = 0.f, a2 = 0.f, a3 = 0.f;
#pragma unroll 4
    for (int f = 0; f < 96; ++f) {
      float4 wv = wr[f], qf = qv[f];
      a0 += wv.x * qf.x; a1 += wv.y * qf.y; a2 += wv.z * qf.z; a3 += wv.w * qf.w;
    }
    Qpart[t] = (a0 + a1) + (a2 + a3);
  }
  __syncthreads();
  if (t < D_F)       QnS[t] = Qpart[2 * t] + Qpart[2 * t + 1] + Qb[t];
  else if (t < 112)  QnS[t] = 0.f;
  __syncthreads();
  if (w == 0) {
    float x = QnS[l] * QnS[l];
    if (l < 48) x += QnS[64 + l] * QnS[64 + l];      // QnS[100..111]==0
#pragma unroll
    for (int d = 1; d < 64; d <<= 1) x += __shfl_xor(x, d, 64);
    if (l == 0) rnS = 1.0f / fmaxf(sqrtf(x), 1e-12f);
  }
  __syncthreads();
  if (t < D_F) QnS[t] *= rnS;
  __syncthreads();     // last barrier — waves independent from here

  float QnSv[NT], bias[NT];
#pragma unroll
  for (int nt = 0; nt < NT; ++nt) {
    const int col = nt * 16 + m;
    QnSv[nt] = QnS[col];
    bias[nt] = (col < D_F) ? Vb[col] : 0.f;
  }

  // ================= per-wave tile loop (4 tiles, no barriers) =================
  for (int tt = 0; tt < 4; ++tt) {
    const int s = s0 + (tt << 2) + w;
    const float* vb = v + (size_t)(b * S_DIM + s) * (N_NBR * D_F);

    // ---- A fragments: global -> reg, bf16, fragment order; 2 mt at a time ----
    s16x8 afr[4][KC];
#pragma unroll
    for (int hp = 0; hp < 2; ++hp) {
      f32x4 L[2][KC], H[2][KC];
#pragma unroll
      for (int i = 0; i < 2; ++i) {
        const int mt  = hp * 2 + i;
        const int row = mt * 16 + m;
        const bool rv = row < N_NBR;                 // rows 50..63: zeros
        const float* ap = vb + row * D_F;
#pragma unroll
        for (int c = 0; c < KC; ++c) {
          const int k0 = c * 32 + qd * 8;
          f32x4 z = {0.f, 0.f, 0.f, 0.f};
          L[i][c] = z; H[i][c] = z;
          if (rv && k0 <= 96) L[i][c] = *(const f32x4*)(ap + k0);      // k0..k0+3 < 100
          if (rv && k0 <= 92) H[i][c] = *(const f32x4*)(ap + k0 + 4);  // k0+4..k0+7 < 100
        }
      }
#pragma unroll
      for (int i = 0; i < 2; ++i)
#pragma unroll
        for (int c = 0; c < KC; ++c) {
          s16x8 pa;
#pragma unroll
          for (int j = 0; j < 4; ++j) { pa[j] = f2bf(L[i][c][j]); pa[4 + j] = f2bf(H[i][c][j]); }
          afr[hp * 2 + i][c] = pa;
        }
    }

    // ---- MFMA: acc[mt][nt] = v_tile @ Vw^T + Vb  (bias pre-loaded in C) ----
    f32x4 acc[4][NT];
#pragma unroll
    for (int mt = 0; mt < 4; ++mt)
#pragma unroll
      for (int nt = 0; nt < NT; ++nt) {
        f32x4 bz; bz[0] = bias[nt]; bz[1] = bias[nt]; bz[2] = bias[nt]; bz[3] = bias[nt];
        acc[mt][nt] = bz;
      }
#pragma unroll
    for (int c = 0; c < KC; ++c) {
      s16x8 bf[NT];
#pragma unroll
      for (int nt = 0; nt < NT; ++nt)
        bf[nt] = *(const s16x8*)&BlS[(((c * 7 + nt) << 6) + l) * 8];   // contiguous, conflict-free
#pragma unroll
      for (int mt = 0; mt < 4; ++mt)
#pragma unroll
        for (int nt = 0; nt < NT; ++nt)
          acc[mt][nt] = __builtin_amdgcn_mfma_f32_16x16x32_bf16(afr[mt][c], bf[nt], acc[mt][nt], 0, 0, 0);
    }

    // ---- scores: R2-verbatim arithmetic; write row values to per-wave LDS ----
#pragma unroll
    for (int mt = 0; mt < 4; ++mt)
#pragma unroll
      for (int r = 0; r < 4; ++r) {
        float np = 0.f, sp = 0.f;
#pragma unroll
        for (int nt = 0; nt < NT; ++nt) {
          const float kv = acc[mt][nt][r];   // row = 16mt+4qd+r, col = 16nt+m
          np += kv * kv;
          sp += QnSv[nt] * kv;
        }
#pragma unroll
        for (int d = 1; d < 16; d <<= 1) {
          np += __shfl_xor(np, d, 64);
          sp += __shfl_xor(sp, d, 64);
        }
        if (m == 0) {
          const int row = mt * 16 + qd * 4 + r;
          nrm2W[w][row] = np; srwW[w][row] = sp;
        }
      }

    // ---- softmax: R2-verbatim, one row per lane (same-wave LDS, no barrier) ----
    {
      float a = -1e30f;
      if (l < N_NBR) {
        float l2 = sqrtf(nrm2W[w][l]);
        if (l2 == 0.f) l2 = 1e-6f;            // where(l2==0, 1e-6)
        float sc = srwW[w][l] / l2;           // cosine similarity
        if (sc == 0.f) sc = -10000.f;         // where(att==0, -10000)
        a = (sc >= 0.f) ? sc : 0.01f * sc;    // leaky_relu 0.01
      }
      float mx = a;
#pragma unroll
      for (int d = 1; d < 64; d <<= 1) mx = fmaxf(mx, __shfl_xor(mx, d, 64));
      const float e = (l < N_NBR) ? __expf(a - mx) : 0.f;
      float sm = e;
#pragma unroll
      for (int d = 1; d < 64; d <<= 1) sm += __shfl_xor(sm, d, 64);
      float att = e / sm;                     // DIVISION — matches R2 & np ref
      if (att == 0.02f) att = 0.f;            // where(att == 1/50, 0)
      attW[w][l] = (l < N_NBR) ? att : 0.f;
    }

    // ---- epilogue: out[col] = sum_n att[n] * K[n][col], in-register ----
    float ar[4][4];
#pragma unroll
    for (int mt = 0; mt < 4; ++mt)
#pragma unroll
      for (int r = 0; r < 4; ++r)
        ar[mt][r] = attW[w][mt * 16 + qd * 4 + r];   // broadcast read per qd-group

    float o[NT];
#pragma unroll
    for (int nt = 0; nt < NT; ++nt) {
      float ov = 0.f;
#pragma unroll
      for (int mt = 0; mt < 4; ++mt)
#pragma unroll
        for (int r = 0; r < 4; ++r)
          ov = fmaf(ar[mt][r], acc[mt][nt][r], ov);  // rows>=50 have att==0
      ov += __shfl_xor(ov, 16, 64);
      ov += __shfl_xor(ov, 32, 64);
      o[nt] = ov;                                    // all lanes hold full col sum
    }
    // coalesced store: col=l gets o[qd]; col=64+l gets o[4+qd]
    const float slo = (qd == 0) ? o[0] : (qd == 1) ? o[1] : (qd == 2) ? o[2] : o[3];
    const float shi = (qd == 0) ? o[4] : (qd == 1) ? o[5] : o[6];
    float* op = out + (size_t)(b * S_DIM + s) * D_F;
    op[l] = slo;
    if (l < 36) op[64 + l] = shi;
  }
}

extern "C" void kernel_launch(void* const* d_in, const int* in_sizes, int n_in,
                              void* d_out, int out_size, void* d_ws, size_t ws_size,
                              hipStream_t stream) {
  const float* q  = (const float*)d_in[1];
  const float* v  = (const float*)d_in[3];
  const float* Qw = (const float*)d_in[4];
  const float* Qb = (const float*)d_in[5];
  const float* Vw = (const float*)d_in[6];
  const float* Vb = (const float*)d_in[7];
  float* out = (float*)d_out;
  (void)d_ws; (void)ws_size;

  wga_kernel<<<512, 256, 0, stream>>>(v, q, Qw, Qb, Vw, Vb, out);
}

// Round 4
// 349.079 us; speedup vs baseline: 1.1417x; 1.1417x over previous
//
#include <hip/hip_runtime.h>
#include <math.h>

// Word_Graph_Attention R5 (resubmit — previous bench was an infra failure:
// "MI355X container failed twice"; kernel never measured).
//
// Wave-per-tile + spill-free register budget.
//
// R4 post-mortem: passed, but 169us/dispatch with WRITE_SIZE 92MB (out is
// 3.3MB) and FETCH_SIZE 245MB (v is 164MB) -- ~80MB symmetric scratch
// round-trip = VGPR spills. Live set was acc(112) + afr(64) + L/H(64) + bf(28)
// ~270 regs. R5 keeps the verified wave-per-tile dataflow but shrinks peak
// VGPR demand: single-c pipeline Lb/Hb[4] (32) + pa[4] (16) + bf[7] (28,
// re-read from LDS per c) + acc(112, AGPR). c/tt loops are '#pragma unroll 1'
// so the compiler cannot rename pipeline buffers into R4's blow-up.
// Explicit prefetch: next-c (or next-tile c=0) loads issue between convert
// and MFMA -> MFMA + softmax/epilogue hide global latency.
// Accumulation order over c unchanged -> K/att/out bit-identical to R4 (pass
// at absmax 3.9e-3, incl. the att==0.02 exact-equality landmine).
//
// Verified layouts (from passing R2/R4):
//   A-frag: lane l holds A[16*mt + (l&15)][c*32 + (l>>4)*8 + j], j=0..7
//   B-frag: lane l holds Vw[16*nt + (l&15)][c*32 + (l>>4)*8 + j]
//   C/D   : acc[mt][nt][r] = K[16*mt + 4*qd + r][16*nt + m]
// No d_ws use (R1 post-mortem: unchecked ws overflow corrupted inputs).

#define S_DIM 256
#define N_NBR 50
#define D_F   100
#define QD    768
#define NT    7      // 7 x 16 = 112 >= 100 output cols
#define KC    4      // 4 x 32 = 128 >= 100 contraction

typedef __attribute__((ext_vector_type(4))) float f32x4;
typedef __attribute__((ext_vector_type(8))) short s16x8;

__device__ __forceinline__ short f2bf(float f) {
  union { float f; unsigned u; } x; x.f = f;
  unsigned r = x.u + 0x7fffu + ((x.u >> 16) & 1u);   // RNE
  return (short)(r >> 16);
}

__global__ __launch_bounds__(256, 2) void wga_kernel(
    const float* __restrict__ v, const float* __restrict__ q,
    const float* __restrict__ Qw, const float* __restrict__ Qb,
    const float* __restrict__ Vw, const float* __restrict__ Vb,
    float* __restrict__ out) {
  __shared__ __align__(16) short BlS[28 * 64 * 8];   // 28 KB B fragments (bf16)
  __shared__ float qs[QD];
  __shared__ float Qpart[256];
  __shared__ float QnS[112];
  __shared__ float rnS;
  __shared__ float nrm2W[4][64], srwW[4][64], attW[4][64];  // per-wave, no races

  const int t  = threadIdx.x;
  const int w  = t >> 6, l = t & 63;
  const int qd = l >> 4, m = l & 15;
  const int blk = blockIdx.x;
  const int b   = blk >> 4;
  const int s0  = (blk & 15) << 4;

  // ---- stage q[b] ----
  for (int i = t; i < QD; i += 256) qs[i] = q[b * QD + i];

  // ---- stage B fragments: BlS[(c*7+nt)*64+ll] = Vw[16nt+(ll&15)][c*32+(ll>>4)*8+j] ----
  for (int idx = t; idx < 28 * 64; idx += 256) {
    const int g  = idx >> 6, ll = idx & 63;
    const int c  = g / 7, nt = g - 7 * c;
    const int col = nt * 16 + (ll & 15);
    const int k0  = c * 32 + (ll >> 4) * 8;
    s16x8 pk;
    if (c < 3 && col < D_F) {                        // fast path: k0+7 <= 95 < 100
      const f32x4 u0 = *(const f32x4*)(Vw + col * D_F + k0);
      const f32x4 u1 = *(const f32x4*)(Vw + col * D_F + k0 + 4);
#pragma unroll
      for (int j = 0; j < 4; ++j) { pk[j] = f2bf(u0[j]); pk[4 + j] = f2bf(u1[j]); }
    } else {
#pragma unroll
      for (int j = 0; j < 8; ++j) {
        const int k = k0 + j;
        pk[j] = f2bf((col < D_F && k < D_F) ? Vw[col * D_F + k] : 0.f);
      }
    }
    *(s16x8*)&BlS[idx * 8] = pk;
  }
  __syncthreads();

  // ---- Qn = normalize(q[b] @ Qw^T + Qb)  (verified R2 code, setup-only) ----
  if (t < 200) {
    const int e = t >> 1, h = t & 1;
    const float4* wr = (const float4*)(Qw + e * QD + h * 384);
    const float4* qv = (const float4*)(qs + h * 384);
    float a0 = 0.f, a1 = 0.f, a2 = 0.f, a3 = 0.f;
#pragma unroll 4
    for (int f = 0; f < 96; ++f) {
      float4 wv = wr[f], qf = qv[f];
      a0 += wv.x * qf.x; a1 += wv.y * qf.y; a2 += wv.z * qf.z; a3 += wv.w * qf.w;
    }
    Qpart[t] = (a0 + a1) + (a2 + a3);
  }
  __syncthreads();
  if (t < D_F)       QnS[t] = Qpart[2 * t] + Qpart[2 * t + 1] + Qb[t];
  else if (t < 112)  QnS[t] = 0.f;
  __syncthreads();
  if (w == 0) {
    float x = QnS[l] * QnS[l];
    if (l < 48) x += QnS[64 + l] * QnS[64 + l];      // QnS[100..111]==0
#pragma unroll
    for (int d = 1; d < 64; d <<= 1) x += __shfl_xor(x, d, 64);
    if (l == 0) rnS = 1.0f / fmaxf(sqrtf(x), 1e-12f);
  }
  __syncthreads();
  if (t < D_F) QnS[t] *= rnS;
  __syncthreads();     // last barrier — waves independent from here

  float QnSv[NT], bias[NT];
#pragma unroll
  for (int nt = 0; nt < NT; ++nt) {
    const int col = nt * 16 + m;
    QnSv[nt] = QnS[col];
    bias[nt] = (col < D_F) ? Vb[col] : 0.f;
  }

  // ---- single-c A pipeline: Lb/Hb hold the in-flight loads (32 VGPR) ----
  f32x4 Lb[4], Hb[4];
  auto loadA = [&](int tti, int c) {
    const int ss = s0 + (tti << 2) + w;
    const float* vbp = v + (size_t)(b * S_DIM + ss) * (N_NBR * D_F);
    const int k0 = c * 32 + qd * 8;
#pragma unroll
    for (int mt = 0; mt < 4; ++mt) {
      const int row = mt * 16 + m;
      const bool rv = row < N_NBR;                   // rows 50..63: zeros
      const float* ap = vbp + row * D_F + k0;
      f32x4 z = {0.f, 0.f, 0.f, 0.f};
      Lb[mt] = z; Hb[mt] = z;
      if (rv && k0 <= 96) Lb[mt] = *(const f32x4*)(ap);      // k0..k0+3 < 100
      if (rv && k0 <= 92) Hb[mt] = *(const f32x4*)(ap + 4);  // k0+4..k0+7 < 100
    }
  };

  loadA(0, 0);   // prologue: tile 0, c=0

  // ================= per-wave tile loop (4 tiles, no barriers) =================
#pragma unroll 1
  for (int tt = 0; tt < 4; ++tt) {
    // ---- acc init with bias (C-in of first MFMA) ----
    f32x4 acc[4][NT];
#pragma unroll
    for (int mt = 0; mt < 4; ++mt)
#pragma unroll
      for (int nt = 0; nt < NT; ++nt) {
        f32x4 bz; bz[0] = bias[nt]; bz[1] = bias[nt]; bz[2] = bias[nt]; bz[3] = bias[nt];
        acc[mt][nt] = bz;
      }

    // ---- MFMA K-loop: convert current c, prefetch next, multiply ----
#pragma unroll 1
    for (int c = 0; c < KC; ++c) {
      s16x8 pa[4];
#pragma unroll
      for (int mt = 0; mt < 4; ++mt) {
        s16x8 p;
#pragma unroll
        for (int j = 0; j < 4; ++j) { p[j] = f2bf(Lb[mt][j]); p[4 + j] = f2bf(Hb[mt][j]); }
        pa[mt] = p;
      }
      if (c < KC - 1)      loadA(tt, c + 1);   // in flight under MFMAs
      else if (tt < 3)     loadA(tt + 1, 0);   // in flight under softmax/epilogue

      s16x8 bf[NT];
#pragma unroll
      for (int nt = 0; nt < NT; ++nt)
        bf[nt] = *(const s16x8*)&BlS[(((c * 7 + nt) << 6) + l) * 8];   // conflict-free
#pragma unroll
      for (int mt = 0; mt < 4; ++mt)
#pragma unroll
        for (int nt = 0; nt < NT; ++nt)
          acc[mt][nt] = __builtin_amdgcn_mfma_f32_16x16x32_bf16(pa[mt], bf[nt], acc[mt][nt], 0, 0, 0);
    }

    // ---- scores: R2/R4-verbatim arithmetic; row values via per-wave LDS ----
#pragma unroll
    for (int mt = 0; mt < 4; ++mt)
#pragma unroll
      for (int r = 0; r < 4; ++r) {
        float np = 0.f, sp = 0.f;
#pragma unroll
        for (int nt = 0; nt < NT; ++nt) {
          const float kv = acc[mt][nt][r];   // row = 16mt+4qd+r, col = 16nt+m
          np += kv * kv;
          sp += QnSv[nt] * kv;
        }
#pragma unroll
        for (int d = 1; d < 16; d <<= 1) {
          np += __shfl_xor(np, d, 64);
          sp += __shfl_xor(sp, d, 64);
        }
        if (m == 0) {
          const int row = mt * 16 + qd * 4 + r;
          nrm2W[w][row] = np; srwW[w][row] = sp;
        }
      }

    // ---- softmax: R2/R4-verbatim, one row per lane (same-wave LDS) ----
    {
      float a = -1e30f;
      if (l < N_NBR) {
        float l2 = sqrtf(nrm2W[w][l]);
        if (l2 == 0.f) l2 = 1e-6f;            // where(l2==0, 1e-6)
        float sc = srwW[w][l] / l2;           // cosine similarity
        if (sc == 0.f) sc = -10000.f;         // where(att==0, -10000)
        a = (sc >= 0.f) ? sc : 0.01f * sc;    // leaky_relu 0.01
      }
      float mx = a;
#pragma unroll
      for (int d = 1; d < 64; d <<= 1) mx = fmaxf(mx, __shfl_xor(mx, d, 64));
      const float e = (l < N_NBR) ? __expf(a - mx) : 0.f;
      float sm = e;
#pragma unroll
      for (int d = 1; d < 64; d <<= 1) sm += __shfl_xor(sm, d, 64);
      float att = e / sm;                     // DIVISION — matches np ref
      if (att == 0.02f) att = 0.f;            // where(att == 1/50, 0)
      attW[w][l] = (l < N_NBR) ? att : 0.f;
    }

    // ---- epilogue: out[col] = sum_n att[n] * K[n][col], in-register ----
    float ar[4][4];
#pragma unroll
    for (int mt = 0; mt < 4; ++mt)
#pragma unroll
      for (int r = 0; r < 4; ++r)
        ar[mt][r] = attW[w][mt * 16 + qd * 4 + r];   // broadcast read per qd-group

    float o[NT];
#pragma unroll
    for (int nt = 0; nt < NT; ++nt) {
      float ov = 0.f;
#pragma unroll
      for (int mt = 0; mt < 4; ++mt)
#pragma unroll
        for (int r = 0; r < 4; ++r)
          ov = fmaf(ar[mt][r], acc[mt][nt][r], ov);  // rows>=50 have att==0
      ov += __shfl_xor(ov, 16, 64);
      ov += __shfl_xor(ov, 32, 64);
      o[nt] = ov;                                    // all lanes hold full col sum
    }
    // coalesced store: col=l gets o[qd]; col=64+l gets o[4+qd]
    const int s = s0 + (tt << 2) + w;
    const float slo = (qd == 0) ? o[0] : (qd == 1) ? o[1] : (qd == 2) ? o[2] : o[3];
    const float shi = (qd == 0) ? o[4] : (qd == 1) ? o[5] : o[6];
    float* op = out + (size_t)(b * S_DIM + s) * D_F;
    op[l] = slo;
    if (l < 36) op[64 + l] = shi;
  }
}

extern "C" void kernel_launch(void* const* d_in, const int* in_sizes, int n_in,
                              void* d_out, int out_size, void* d_ws, size_t ws_size,
                              hipStream_t stream) {
  const float* q  = (const float*)d_in[1];
  const float* v  = (const float*)d_in[3];
  const float* Qw = (const float*)d_in[4];
  const float* Qb = (const float*)d_in[5];
  const float* Vw = (const float*)d_in[6];
  const float* Vb = (const float*)d_in[7];
  float* out = (float*)d_out;
  (void)d_ws; (void)ws_size;

  wga_kernel<<<512, 256, 0, stream>>>(v, q, Qw, Qb, Vw, Vb, out);
}